// Round 9
// baseline (120.246 us; speedup 1.0000x reference)
//
#include <hip/hip_runtime.h>
#include <hip/hip_cooperative_groups.h>
#include <cstdint>
#include <math.h>

namespace cg = cooperative_groups;

#define N_FRAMES 16777216          // 2^24
#define MAX_BEATS (N_FRAMES / 8)   // 2097152
#define CHUNK 4096
#define NTHREADS 256
#define NCHUNK (N_FRAMES / CHUNK)  // 4096 chunks
#define GRID (NCHUNK / 4)          // 1024 blocks, 4 chunks each (co-resident: 4/CU)
#define NBLK (NCHUNK / 4)          // fallback emit blocks
#define TOTAL_MASKS ((size_t)NCHUNK * 64)

typedef unsigned long long u64;
typedef unsigned int u32;

__device__ __forceinline__ float max3f(float a, float b, float c) {
  return fmaxf(fmaxf(a, b), c);
}

// stencil for 16 elems at gbase: fills pm (peak bits) and pm1 (peak at gbase-1)
__device__ __forceinline__ void stencil16(const float* __restrict__ x, int gbase,
                                          u32& pm, u32& pm1) {
  float v[24];
  if (gbase - 4 >= 0 && gbase + 20 <= N_FRAMES) {
    const float4* p = reinterpret_cast<const float4*>(x + gbase - 4);
#pragma unroll
    for (int k = 0; k < 6; ++k) {
      const float4 f = p[k];
      v[4 * k + 0] = f.x; v[4 * k + 1] = f.y; v[4 * k + 2] = f.z; v[4 * k + 3] = f.w;
    }
  } else {
#pragma unroll
    for (int k = 0; k < 24; ++k) {
      const int gi = gbase - 4 + k;
      v[k] = (gi >= 0 && gi < N_FRAMES) ? x[gi] : -INFINITY;
    }
  }
  float Lt[21];
#pragma unroll
  for (int i = 0; i < 21; ++i) Lt[i] = max3f(v[i], v[i + 1], v[i + 2]);
  pm = 0;
#pragma unroll
  for (int e = 0; e < 16; ++e) {
    const float c = v[e + 4];
    const float m = fmaxf(Lt[e + 1], Lt[e + 5]);
    if (c > 0.0f && c >= m) pm |= (1u << e);
  }
  const float cm1 = v[3];
  pm1 = (cm1 > 0.0f && cm1 >= fmaxf(Lt[0], Lt[4])) ? 1u : 0u;
}

// ---------------- fused cooperative kernel ----------------
__global__ __launch_bounds__(NTHREADS, 4) void k_fused(const float* __restrict__ x,
                                                       int* __restrict__ counts,
                                                       u64* __restrict__ masks,
                                                       float* __restrict__ out) {
  __shared__ u32 m16[4][NTHREADS];   // per-chunk 16-bit masks
  __shared__ u32 s_pm1[4];
  __shared__ int s_wtot[4];
  __shared__ int s_texcl[NTHREADS];
  __shared__ int s_off[4];
  const int t = threadIdx.x, lane = t & 63, wv = t >> 6;

  // ---- phase 1: masks + per-chunk counts for chunks 4B..4B+3 ----
#pragma unroll
  for (int c = 0; c < 4; ++c) {
    const int b = blockIdx.x * 4 + c;
    u32 pm, pm1;
    stencil16(x, b * CHUNK + t * 16, pm, pm1);
    m16[c][t] = pm;
    if (t == 0) s_pm1[c] = pm1;
  }
  __syncthreads();
  {
    const int c = wv;                // wave c packs/counts chunk c
    const u64 m = (u64)m16[c][4 * lane] | ((u64)m16[c][4 * lane + 1] << 16) |
                  ((u64)m16[c][4 * lane + 2] << 32) | ((u64)m16[c][4 * lane + 3] << 48);
    const int b = blockIdx.x * 4 + c;
    masks[((size_t)b << 6) + lane] = m;   // global mirror (tie-walk only)
    const u64 carry = (lane == 0) ? (u64)s_pm1[c]
                                  : (u64)((m16[c][4 * lane - 1] >> 15) & 1u);
    int cnt = __popcll(m & ~((m << 1) | carry));
#pragma unroll
    for (int off = 32; off; off >>= 1) cnt += __shfl_down(cnt, off, 64);
    if (lane == 0) counts[b] = cnt;
  }

  cg::this_grid().sync();

  // ---- phase 2: inlined global scan over counts[NCHUNK] + emit ----
  int s = 0;
  const int cb = t * 16;
#pragma unroll
  for (int e = 0; e < 16; ++e) s += counts[cb + e];
  int incl = s;
#pragma unroll
  for (int off = 1; off < 64; off <<= 1) {
    const int vv = __shfl_up(incl, off, 64);
    if (lane >= off) incl += vv;
  }
  s_texcl[t] = incl - s;
  if (lane == 63) s_wtot[wv] = incl;
  __syncthreads();
  if (t < 4) {   // offset of chunk blockIdx.x*4 + t
    const int target = blockIdx.x * 4 + t;
    const int j = target >> 4, r = target & 15;
    int wb = 0;
    for (int ww = 0; ww < (j >> 6); ++ww) wb += s_wtot[ww];
    int pfx = wb + s_texcl[j];
    for (int e = 0; e < r; ++e) pfx += counts[j * 16 + e];
    s_off[t] = pfx;
  }
  __syncthreads();
  const int s_total = s_wtot[0] + s_wtot[1] + s_wtot[2] + s_wtot[3];

  const int b = blockIdx.x * 4 + wv;
  const size_t mi = ((size_t)b << 6) + lane;
  const u64 m = (u64)m16[wv][4 * lane] | ((u64)m16[wv][4 * lane + 1] << 16) |
                ((u64)m16[wv][4 * lane + 2] << 32) | ((u64)m16[wv][4 * lane + 3] << 48);
  const u32 myb63 = (u32)(m >> 63);
  u32 prevb = __shfl_up(myb63, 1, 64);
  if (lane == 0) prevb = (b == 0) ? 0u : (u32)(masks[mi - 1] >> 63);
  u64 sm = m & ~((m << 1) | (u64)prevb);
  const int cnt = __popcll(sm);

  int incl2 = cnt;
#pragma unroll
  for (int off = 1; off < 64; off <<= 1) {
    const int vv = __shfl_up(incl2, off, 64);
    if (lane >= off) incl2 += vv;
  }
  int sid = s_off[wv] + incl2 - cnt;

  if (s_off[wv] < MAX_BEATS) {
    const int gbase = b * CHUNK + lane * 64;
    while (sm) {
      const int sb = __builtin_ctzll(sm);
      sm &= sm - 1;
      const int i0 = gbase + sb;
      const u64 above = m >> sb;
      const int len = (~above == 0ull) ? (64 - sb) : __builtin_ctzll(~above);
      int end = i0 + len - 1;
      if (sb + len == 64) {              // run continues into next mask (ties; rare)
        size_t idx = mi + 1;
        while (idx < TOTAL_MASKS) {
          const u64 mm = masks[idx];
          if (~mm == 0ull) { end += 64; ++idx; }
          else { end += __builtin_ctzll(~mm); break; }
        }
      }
      if (sid < MAX_BEATS)
        out[sid] = (float)(((double)i0 + (double)end) * 0.5);
      ++sid;
    }
  }

  // -1 tail fill: block covers out[blockIdx*2048 .. +2048)
  const int lo = blockIdx.x * (MAX_BEATS / GRID);
  const int hi = lo + (MAX_BEATS / GRID);
  for (int i = max(lo, s_total) + t; i < hi; i += NTHREADS)
    out[i] = -1.0f;
}

// ---------------- fallback: proven R7 two-kernel path ----------------
__global__ __launch_bounds__(NTHREADS) void k_count(const float* __restrict__ x,
                                                    int* __restrict__ counts,
                                                    u64* __restrict__ masks) {
  __shared__ u32 m16[NTHREADS];
  __shared__ u32 s_pm1;
  const int b = blockIdx.x;
  const int t = threadIdx.x;
  u32 pm, pm1;
  stencil16(x, b * CHUNK + t * 16, pm, pm1);
  m16[t] = pm;
  if (t == 0) s_pm1 = pm1;
  __syncthreads();
  if (t < 64) {
    const u64 m = (u64)m16[4 * t] | ((u64)m16[4 * t + 1] << 16) |
                  ((u64)m16[4 * t + 2] << 32) | ((u64)m16[4 * t + 3] << 48);
    masks[((size_t)b << 6) + t] = m;
    const u64 carry = (t == 0) ? (u64)s_pm1 : (u64)((m16[4 * t - 1] >> 15) & 1u);
    int cnt = __popcll(m & ~((m << 1) | carry));
#pragma unroll
    for (int off = 32; off; off >>= 1) cnt += __shfl_down(cnt, off, 64);
    if (t == 0) counts[b] = cnt;
  }
}

__global__ __launch_bounds__(NTHREADS) void k_emit(const u64* __restrict__ masks,
                                                   const int* __restrict__ counts,
                                                   float* __restrict__ out) {
  __shared__ int s_wtot[4];
  __shared__ int s_texcl[NTHREADS];
  __shared__ int s_off[4];
  __shared__ int s_total;
  const int t = threadIdx.x, lane = t & 63, wv = t >> 6;
  int s = 0;
  const int cb = t * 16;
#pragma unroll
  for (int e = 0; e < 16; ++e) s += counts[cb + e];
  int incl = s;
#pragma unroll
  for (int off = 1; off < 64; off <<= 1) {
    const int vv = __shfl_up(incl, off, 64);
    if (lane >= off) incl += vv;
  }
  s_texcl[t] = incl - s;
  if (lane == 63) s_wtot[wv] = incl;
  __syncthreads();
  if (t == 0) s_total = s_wtot[0] + s_wtot[1] + s_wtot[2] + s_wtot[3];
  if (t < 4) {
    const int target = blockIdx.x * 4 + t;
    const int j = target >> 4, r = target & 15;
    int wb = 0;
    for (int ww = 0; ww < (j >> 6); ++ww) wb += s_wtot[ww];
    int pfx = wb + s_texcl[j];
    for (int e = 0; e < r; ++e) pfx += counts[j * 16 + e];
    s_off[t] = pfx;
  }
  __syncthreads();

  const int b = blockIdx.x * 4 + wv;
  const size_t mi = ((size_t)b << 6) + lane;
  const u64 m = masks[mi];
  const u32 myb63 = (u32)(m >> 63);
  u32 prevb = __shfl_up(myb63, 1, 64);
  if (lane == 0) prevb = (b == 0) ? 0u : (u32)(masks[mi - 1] >> 63);
  u64 sm = m & ~((m << 1) | (u64)prevb);
  const int cnt = __popcll(sm);
  int incl2 = cnt;
#pragma unroll
  for (int off = 1; off < 64; off <<= 1) {
    const int vv = __shfl_up(incl2, off, 64);
    if (lane >= off) incl2 += vv;
  }
  int sid = s_off[wv] + incl2 - cnt;
  if (s_off[wv] < MAX_BEATS) {
    const int gbase = b * CHUNK + lane * 64;
    while (sm) {
      const int sb = __builtin_ctzll(sm);
      sm &= sm - 1;
      const int i0 = gbase + sb;
      const u64 above = m >> sb;
      const int len = (~above == 0ull) ? (64 - sb) : __builtin_ctzll(~above);
      int end = i0 + len - 1;
      if (sb + len == 64) {
        size_t idx = mi + 1;
        while (idx < TOTAL_MASKS) {
          const u64 mm = masks[idx];
          if (~mm == 0ull) { end += 64; ++idx; }
          else { end += __builtin_ctzll(~mm); break; }
        }
      }
      if (sid < MAX_BEATS)
        out[sid] = (float)(((double)i0 + (double)end) * 0.5);
      ++sid;
    }
  }
  const int lo = blockIdx.x * (MAX_BEATS / NBLK);
  const int hi = lo + (MAX_BEATS / NBLK);
  for (int i = max(lo, s_total) + t; i < hi; i += NTHREADS)
    out[i] = -1.0f;
}

extern "C" void kernel_launch(void* const* d_in, const int* in_sizes, int n_in,
                              void* d_out, int out_size, void* d_ws, size_t ws_size,
                              hipStream_t stream) {
  const float* xp = (const float*)d_in[0];
  float* outp = (float*)d_out;
  u64* masks = (u64*)d_ws;                      // 2 MiB
  int* counts = (int*)(masks + TOTAL_MASKS);    // 16 KiB

  void* args[] = {(void*)&xp, (void*)&counts, (void*)&masks, (void*)&outp};
  hipError_t err = hipLaunchCooperativeKernel((const void*)k_fused, dim3(GRID),
                                              dim3(NTHREADS), args, 0, stream);
  if (err != hipSuccess) {   // fallback: proven two-kernel path
    k_count<<<NCHUNK, NTHREADS, 0, stream>>>(xp, counts, masks);
    k_emit<<<NBLK, NTHREADS, 0, stream>>>(masks, counts, outp);
  }
}

// Round 10
// 28.941 us; speedup vs baseline: 4.1549x; 4.1549x over previous
//
#include <hip/hip_runtime.h>
#include <cstdint>
#include <math.h>

#define N_FRAMES 16777216          // 2^24
#define MAX_BEATS (N_FRAMES / 8)   // 2097152
#define CHUNK 4096                 // emit-side chunk (mask/count granularity)
#define NTHREADS 256
#define NCHUNK (N_FRAMES / CHUNK)  // 4096
#define BCHUNK 8192                // k_count block span (2 chunks)
#define NCBLK (N_FRAMES / BCHUNK)  // 2048 k_count blocks
#define NBLK (NCHUNK / 4)          // 1024 emit blocks (4 waves, 1 chunk each)
#define TOTAL_MASKS ((size_t)NCHUNK * 64)

typedef unsigned long long u64;
typedef unsigned int u32;

__device__ __forceinline__ float max3f(float a, float b, float c) {
  return fmaxf(fmaxf(a, b), c);
}

// stencil for 16 elems at gbase: pm = peak bits, pm1 = peak at gbase-1
__device__ __forceinline__ void stencil16(const float* __restrict__ x, int gbase,
                                          u32& pm, u32& pm1) {
  float v[24];
  if (gbase - 4 >= 0 && gbase + 20 <= N_FRAMES) {
    const float4* p = reinterpret_cast<const float4*>(x + gbase - 4);
#pragma unroll
    for (int k = 0; k < 6; ++k) {
      const float4 f = p[k];
      v[4 * k + 0] = f.x; v[4 * k + 1] = f.y; v[4 * k + 2] = f.z; v[4 * k + 3] = f.w;
    }
  } else {
#pragma unroll
    for (int k = 0; k < 24; ++k) {
      const int gi = gbase - 4 + k;
      v[k] = (gi >= 0 && gi < N_FRAMES) ? x[gi] : -INFINITY;
    }
  }
  float Lt[21];
#pragma unroll
  for (int i = 0; i < 21; ++i) Lt[i] = max3f(v[i], v[i + 1], v[i + 2]);
  pm = 0;
#pragma unroll
  for (int e = 0; e < 16; ++e) {
    const float c = v[e + 4];
    const float m = fmaxf(Lt[e + 1], Lt[e + 5]);
    if (c > 0.0f && c >= m) pm |= (1u << e);
  }
  const float cm1 = v[3];
  pm1 = (cm1 > 0.0f && cm1 >= fmaxf(Lt[0], Lt[4])) ? 1u : 0u;  // local carry
}

// process one 1024-elem wave segment: returns run-start count (per-thread),
// lanes 0..15 store the 16 u64 mask rows via shfl-pack (no LDS).
__device__ __forceinline__ int do_segment(const float* __restrict__ x,
                                          u64* __restrict__ masks,
                                          int chunk4k, int wv, int lane, int gbase) {
  u32 pm, pm1;
  stencil16(x, gbase, pm, pm1);
  const int cnt = __popc(pm & ~((pm << 1) | pm1));
  // lane l<16 packs rows 16*wv + l (row = 64 elems = lanes 4l..4l+3)
  const u32 a = __shfl(pm, 4 * lane + 0, 64);
  const u32 b = __shfl(pm, 4 * lane + 1, 64);
  const u32 c = __shfl(pm, 4 * lane + 2, 64);
  const u32 d = __shfl(pm, 4 * lane + 3, 64);
  if (lane < 16) {
    const u64 m = (u64)a | ((u64)b << 16) | ((u64)c << 32) | ((u64)d << 48);
    masks[((size_t)chunk4k << 6) + 16 * wv + lane] = m;
  }
  return cnt;
}

// k_count: 2048 blocks x 8192 elems; wave wv handles segment wv of both
// sub-chunks. No LDS mask exchange; single tiny count reduce.
__global__ __launch_bounds__(NTHREADS) void k_count(const float* __restrict__ x,
                                                    int* __restrict__ counts,
                                                    u64* __restrict__ masks) {
  __shared__ u32 s_pack[4];
  const int b = blockIdx.x;
  const int t = threadIdx.x, lane = t & 63, wv = t >> 6;
  const int B = b * BCHUNK;

  const int cntA = do_segment(x, masks, 2 * b,     wv, lane, B + 1024 * wv + 16 * lane);
  const int cntB = do_segment(x, masks, 2 * b + 1, wv, lane, B + 4096 + 1024 * wv + 16 * lane);

  u32 packed = (u32)cntA | ((u32)cntB << 16);   // per-half sums < 512, no overflow
#pragma unroll
  for (int off = 32; off; off >>= 1) packed += __shfl_down(packed, off, 64);
  if (lane == 0) s_pack[wv] = packed;
  __syncthreads();
  if (t == 0) {
    const u32 p = s_pack[0] + s_pack[1] + s_pack[2] + s_pack[3];
    counts[2 * b]     = (int)(p & 0xFFFFu);
    counts[2 * b + 1] = (int)(p >> 16);
  }
}

// k_emit: verbatim R7. 4 waves/block, wave wv owns chunk blockIdx.x*4+wv;
// inlines the global scan over counts[NCHUNK] (16 KB, L2-hot).
__global__ __launch_bounds__(NTHREADS) void k_emit(const u64* __restrict__ masks,
                                                   const int* __restrict__ counts,
                                                   float* __restrict__ out) {
  __shared__ int s_wtot[4];
  __shared__ int s_texcl[NTHREADS];
  __shared__ int s_off[4];
  __shared__ int s_total;
  const int t = threadIdx.x, lane = t & 63, wv = t >> 6;

  int s = 0;
  const int cb = t * 16;
#pragma unroll
  for (int e = 0; e < 16; ++e) s += counts[cb + e];
  int incl = s;
#pragma unroll
  for (int off = 1; off < 64; off <<= 1) {
    const int vv = __shfl_up(incl, off, 64);
    if (lane >= off) incl += vv;
  }
  s_texcl[t] = incl - s;
  if (lane == 63) s_wtot[wv] = incl;
  __syncthreads();
  if (t == 0) s_total = s_wtot[0] + s_wtot[1] + s_wtot[2] + s_wtot[3];
  if (t < 4) {   // offset of chunk blockIdx.x*4 + t
    const int target = blockIdx.x * 4 + t;
    const int j = target >> 4, r = target & 15;
    int wb = 0;
    for (int ww = 0; ww < (j >> 6); ++ww) wb += s_wtot[ww];
    int pfx = wb + s_texcl[j];
    for (int e = 0; e < r; ++e) pfx += counts[j * 16 + e];
    s_off[t] = pfx;
  }
  __syncthreads();

  const int b = blockIdx.x * 4 + wv;
  const size_t mi = ((size_t)b << 6) + lane;
  const u64 m = masks[mi];
  const u32 myb63 = (u32)(m >> 63);
  u32 prevb = __shfl_up(myb63, 1, 64);
  if (lane == 0) prevb = (b == 0) ? 0u : (u32)(masks[mi - 1] >> 63);
  u64 sm = m & ~((m << 1) | (u64)prevb);
  const int cnt = __popcll(sm);

  int incl2 = cnt;
#pragma unroll
  for (int off = 1; off < 64; off <<= 1) {
    const int vv = __shfl_up(incl2, off, 64);
    if (lane >= off) incl2 += vv;
  }
  int sid = s_off[wv] + incl2 - cnt;

  if (s_off[wv] < MAX_BEATS) {
    const int gbase = b * CHUNK + lane * 64;
    while (sm) {
      const int sb = __builtin_ctzll(sm);
      sm &= sm - 1;
      const int i0 = gbase + sb;
      const u64 above = m >> sb;           // bit 0 = this peak
      const int len = (~above == 0ull) ? (64 - sb) : __builtin_ctzll(~above);
      int end = i0 + len - 1;
      if (sb + len == 64) {                // run continues into next mask (ties; rare)
        size_t idx = mi + 1;
        while (idx < TOTAL_MASKS) {
          const u64 mm = masks[idx];
          if (~mm == 0ull) { end += 64; ++idx; }
          else { end += __builtin_ctzll(~mm); break; }
        }
      }
      if (sid < MAX_BEATS)
        out[sid] = (float)(((double)i0 + (double)end) * 0.5);
      ++sid;
    }
  }

  // -1 tail fill: this block covers out[blockIdx*2048 .. +2048)
  const int lo = blockIdx.x * (MAX_BEATS / NBLK);
  const int hi = lo + (MAX_BEATS / NBLK);
  for (int i = max(lo, s_total) + t; i < hi; i += NTHREADS)
    out[i] = -1.0f;
}

extern "C" void kernel_launch(void* const* d_in, const int* in_sizes, int n_in,
                              void* d_out, int out_size, void* d_ws, size_t ws_size,
                              hipStream_t stream) {
  const float* x = (const float*)d_in[0];
  float* out = (float*)d_out;

  u64* masks = (u64*)d_ws;                      // 2 MiB
  int* counts = (int*)(masks + TOTAL_MASKS);    // 16 KiB

  k_count<<<NCBLK, NTHREADS, 0, stream>>>(x, counts, masks);
  k_emit<<<NBLK, NTHREADS, 0, stream>>>(masks, counts, out);
}

// Round 11
// 26.720 us; speedup vs baseline: 4.5002x; 1.0831x over previous
//
#include <hip/hip_runtime.h>
#include <cstdint>
#include <math.h>

#define N_FRAMES 16777216          // 2^24
#define MAX_BEATS (N_FRAMES / 8)   // 2097152
#define CHUNK 4096
#define NTHREADS 256
#define NCHUNK (N_FRAMES / CHUNK)  // 4096
#define NBLK (NCHUNK / 4)          // 1024 emit blocks (4 waves, 1 chunk each)
#define TOTAL_MASKS ((size_t)NCHUNK * 64)
#define MAXSEC 2064                // >= max sections/chunk (2048) + pad

typedef unsigned long long u64;
typedef unsigned int u32;

__device__ __forceinline__ float max3f(float a, float b, float c) {
  return fmaxf(fmaxf(a, b), c);
}

// k_count: exact 4x float4 per thread; halos via shfl(+edge loads on lanes 0/63).
// v[k] = x[gbase-4+k], k in [0,23): v[0..3] left halo, v[4..19] own, v[20..22] right.
__global__ __launch_bounds__(NTHREADS) void k_count(const float* __restrict__ x,
                                                    int* __restrict__ counts,
                                                    u64* __restrict__ masks) {
  __shared__ u32 m16[NTHREADS];
  __shared__ u32 s_pm1;
  const int b = blockIdx.x;
  const int t = threadIdx.x;
  const int lane = t & 63;
  const int gbase = b * CHUNK + t * 16;

  float v[23];
  {
    const float4* p = reinterpret_cast<const float4*>(x + gbase);
#pragma unroll
    for (int k = 0; k < 4; ++k) {
      const float4 f = p[k];
      v[4 + 4 * k] = f.x; v[5 + 4 * k] = f.y; v[6 + 4 * k] = f.z; v[7 + 4 * k] = f.w;
    }
  }
  // halos: left = prev thread's last 4 (v[16..19]); right = next thread's first 3
  v[0]  = __shfl_up(v[16], 1, 64);
  v[1]  = __shfl_up(v[17], 1, 64);
  v[2]  = __shfl_up(v[18], 1, 64);
  v[3]  = __shfl_up(v[19], 1, 64);
  v[20] = __shfl_down(v[4], 1, 64);
  v[21] = __shfl_down(v[5], 1, 64);
  v[22] = __shfl_down(v[6], 1, 64);
  if (lane == 0) {   // cross-wave/block left edge
    if (gbase >= 4) {
      const float4 f = *reinterpret_cast<const float4*>(x + gbase - 4);
      v[0] = f.x; v[1] = f.y; v[2] = f.z; v[3] = f.w;
    } else { v[0] = v[1] = v[2] = v[3] = -INFINITY; }
  }
  if (lane == 63) {  // cross-wave/block right edge
    if (gbase + 20 <= N_FRAMES) {
      const float4 f = *reinterpret_cast<const float4*>(x + gbase + 16);
      v[20] = f.x; v[21] = f.y; v[22] = f.z;
    } else { v[20] = v[21] = v[22] = -INFINITY; }
  }

  // trio maxes: Lt[i] = max(v[i..i+2]); window(e) = max(Lt[e+1], Lt[e+5])
  float Lt[21];
#pragma unroll
  for (int i = 0; i < 21; ++i) Lt[i] = max3f(v[i], v[i + 1], v[i + 2]);

  u32 pm = 0;
#pragma unroll
  for (int e = 0; e < 16; ++e) {
    const float c = v[e + 4];
    const float m = fmaxf(Lt[e + 1], Lt[e + 5]);
    if (c > 0.0f && c >= m) pm |= (1u << e);
  }
  m16[t] = pm;
  if (t == 0) {  // peak at g0-1: center v[3], window trios Lt[0], Lt[4]
    const float c = v[3];
    const float m = fmaxf(Lt[0], Lt[4]);
    s_pm1 = (c > 0.0f && c >= m) ? 1u : 0u;
  }
  __syncthreads();

  if (t < 64) {
    const u64 m = (u64)m16[4 * t] | ((u64)m16[4 * t + 1] << 16) |
                  ((u64)m16[4 * t + 2] << 32) | ((u64)m16[4 * t + 3] << 48);
    masks[((size_t)b << 6) + t] = m;
    const u64 carry = (t == 0) ? (u64)s_pm1 : (u64)((m16[4 * t - 1] >> 15) & 1u);
    int cnt = __popcll(m & ~((m << 1) | carry));
#pragma unroll
    for (int off = 32; off; off >>= 1) cnt += __shfl_down(cnt, off, 64);
    if (t == 0) counts[b] = cnt;
  }
}

// k_emit: 4 waves/block, wave wv owns chunk blockIdx.x*4+wv; inlined global scan;
// sections staged in per-wave LDS then flushed with coalesced stores.
__global__ __launch_bounds__(NTHREADS) void k_emit(const u64* __restrict__ masks,
                                                   const int* __restrict__ counts,
                                                   float* __restrict__ out) {
  __shared__ float s_out[4][MAXSEC];   // per-wave contiguous section buffer (33 KB)
  __shared__ int s_wtot[4];
  __shared__ int s_texcl[NTHREADS];
  __shared__ int s_off[4];
  __shared__ int s_total;
  const int t = threadIdx.x, lane = t & 63, wv = t >> 6;

  // global scan recompute: thread t owns counts[16t .. 16t+16) (L2-hot 16 KB)
  int s = 0;
  const int cb = t * 16;
#pragma unroll
  for (int e = 0; e < 16; ++e) s += counts[cb + e];
  int incl = s;
#pragma unroll
  for (int off = 1; off < 64; off <<= 1) {
    const int vv = __shfl_up(incl, off, 64);
    if (lane >= off) incl += vv;
  }
  s_texcl[t] = incl - s;
  if (lane == 63) s_wtot[wv] = incl;
  __syncthreads();
  if (t == 0) s_total = s_wtot[0] + s_wtot[1] + s_wtot[2] + s_wtot[3];
  if (t < 4) {   // offset of chunk blockIdx.x*4 + t
    const int target = blockIdx.x * 4 + t;
    const int j = target >> 4, r = target & 15;
    int wb = 0;
    for (int ww = 0; ww < (j >> 6); ++ww) wb += s_wtot[ww];
    int pfx = wb + s_texcl[j];
    for (int e = 0; e < r; ++e) pfx += counts[j * 16 + e];
    s_off[t] = pfx;
  }
  __syncthreads();

  const int b = blockIdx.x * 4 + wv;
  const size_t mi = ((size_t)b << 6) + lane;
  const u64 m = masks[mi];
  const u32 myb63 = (u32)(m >> 63);
  u32 prevb = __shfl_up(myb63, 1, 64);
  if (lane == 0) prevb = (b == 0) ? 0u : (u32)(masks[mi - 1] >> 63);
  u64 sm = m & ~((m << 1) | (u64)prevb);
  const int cnt = __popcll(sm);

  int incl2 = cnt;
#pragma unroll
  for (int off = 1; off < 64; off <<= 1) {
    const int vv = __shfl_up(incl2, off, 64);
    if (lane >= off) incl2 += vv;
  }
  const int cnt_chunk = __shfl(incl2, 63, 64);   // sections in this chunk
  int sidl = incl2 - cnt;                        // local section index

  if (s_off[wv] < MAX_BEATS) {
    const int gbase = b * CHUNK + lane * 64;
    u64 smw = sm;
    while (smw) {
      const int sb = __builtin_ctzll(smw);
      smw &= smw - 1;
      const int i0 = gbase + sb;
      const u64 above = m >> sb;           // bit 0 = this peak
      const int len = (~above == 0ull) ? (64 - sb) : __builtin_ctzll(~above);
      int end = i0 + len - 1;
      if (sb + len == 64) {                // run continues into next mask (ties; rare)
        size_t idx = mi + 1;
        while (idx < TOTAL_MASKS) {
          const u64 mm = masks[idx];
          if (~mm == 0ull) { end += 64; ++idx; }
          else { end += __builtin_ctzll(~mm); break; }
        }
      }
      s_out[wv][sidl] = (float)(((double)i0 + (double)end) * 0.5);
      ++sidl;
    }
  }
  __syncthreads();   // order LDS section writes before coalesced flush

  if (s_off[wv] < MAX_BEATS) {
    const int off0 = s_off[wv];
    for (int i = lane; i < cnt_chunk; i += 64) {
      const int gi = off0 + i;
      if (gi < MAX_BEATS) out[gi] = s_out[wv][i];
    }
  }

  // -1 tail fill: this block covers out[blockIdx*2048 .. +2048)
  const int lo = blockIdx.x * (MAX_BEATS / NBLK);
  const int hi = lo + (MAX_BEATS / NBLK);
  for (int i = max(lo, s_total) + t; i < hi; i += NTHREADS)
    out[i] = -1.0f;
}

extern "C" void kernel_launch(void* const* d_in, const int* in_sizes, int n_in,
                              void* d_out, int out_size, void* d_ws, size_t ws_size,
                              hipStream_t stream) {
  const float* x = (const float*)d_in[0];
  float* out = (float*)d_out;

  u64* masks = (u64*)d_ws;                      // 2 MiB
  int* counts = (int*)(masks + TOTAL_MASKS);    // 16 KiB

  k_count<<<NCHUNK, NTHREADS, 0, stream>>>(x, counts, masks);
  k_emit<<<NBLK, NTHREADS, 0, stream>>>(masks, counts, out);
}